// Round 1
// baseline (255.549 us; speedup 1.0000x reference)
//
#include <hip/hip_runtime.h>
#include <hip/hip_bf16.h>
#include <cstdint>
#include <cmath>

#define NT 4096      // tokens
#define DIN 512      // input dim
#define DOUT 1280    // total output dim
#define NE 8         // experts
#define TDIM 64      // type-embedding dim

typedef __attribute__((ext_vector_type(8))) short bhalf8;
typedef __attribute__((ext_vector_type(4))) float f32x4;

__device__ __forceinline__ unsigned short f2bf(float f) {
    __hip_bfloat16 h = __float2bfloat16(f);
    return *reinterpret_cast<unsigned short*>(&h);
}

// ---------------------------------------------------------------------------
// K1: gating (fp32 exact) + x -> bf16 conversion. One wave (64 lanes) / token.
// ---------------------------------------------------------------------------
__global__ __launch_bounds__(256) void gate_kernel(
    const float* __restrict__ x, const float* __restrict__ temb,
    const int* __restrict__ atype, const float* __restrict__ Wg,
    unsigned short* __restrict__ xb,
    int* __restrict__ e0a, int* __restrict__ e1a,
    float* __restrict__ g0a, float* __restrict__ g1a,
    int* __restrict__ r0a, int* __restrict__ r1a,
    int* __restrict__ counts)
{
    const int n = blockIdx.x * 4 + (threadIdx.x >> 6);
    const int l = threadIdx.x & 63;
    float acc[NE];
#pragma unroll
    for (int e = 0; e < NE; ++e) acc[e] = 0.f;

    const float* xr = x + (size_t)n * DIN;
#pragma unroll
    for (int i = 0; i < DIN / 64; ++i) {
        const int k = i * 64 + l;
        const float xv = xr[k];
        xb[(size_t)n * DIN + k] = f2bf(xv);           // coalesced 128B/wave
        const float* wr = Wg + (size_t)k * NE;
#pragma unroll
        for (int e = 0; e < NE; ++e) acc[e] = fmaf(xv, wr[e], acc[e]);
    }
    {   // tebd part: lane l covers tebd dim l (TDIM == 64)
        const int t = atype[n];
        const float tv = temb[(size_t)t * TDIM + l];
        const float* wr = Wg + (size_t)(DIN + l) * NE;
#pragma unroll
        for (int e = 0; e < NE; ++e) acc[e] = fmaf(tv, wr[e], acc[e]);
    }
    // wave butterfly reduce (all lanes end with full sums)
#pragma unroll
    for (int off = 32; off > 0; off >>= 1) {
#pragma unroll
        for (int e = 0; e < NE; ++e) acc[e] += __shfl_xor(acc[e], off, 64);
    }
    if (l == 0) {
        // top-2, lowest-index-wins on exact ties (matches jax.lax.top_k)
        int e0 = 0; float v0 = acc[0];
#pragma unroll
        for (int e = 1; e < NE; ++e) if (acc[e] > v0) { v0 = acc[e]; e0 = e; }
        int e1 = -1; float v1 = -INFINITY;
#pragma unroll
        for (int e = 0; e < NE; ++e) {
            if (e == e0) continue;
            if (acc[e] > v1) { v1 = acc[e]; e1 = e; }
        }
        const float p1 = expf(v1 - v0);        // softmax over [v0, v1], v0 = max
        const float s  = 1.f + p1;
        const float g0 = 1.f / s;
        const float g1 = p1 / s;
        e0a[n] = e0; e1a[n] = e1; g0a[n] = g0; g1a[n] = g1;
        r0a[n] = atomicAdd(&counts[e0], 1);
        r1a[n] = atomicAdd(&counts[NE + e1], 1);
    }
}

// ---------------------------------------------------------------------------
// K2: W_exp [e][k][n] f32 -> WT [e][n][k] bf16 (convert + transpose).
// Lane-per-n: reads coalesced across lanes at each k; each thread writes one
// contiguous 64B k-chunk of its n-row.
// ---------------------------------------------------------------------------
__global__ __launch_bounds__(64) void convw_kernel(
    const float* __restrict__ W, unsigned short* __restrict__ WT)
{
    const int n  = blockIdx.x * 64 + threadIdx.x;   // 0..1279
    const int k0 = blockIdx.y * 32;                 // 0..480
    const int e  = blockIdx.z;
    const float* src = W + ((size_t)e * DIN + k0) * DOUT + n;
    unsigned short* dst = WT + ((size_t)e * DOUT + n) * DIN + k0;
    __attribute__((aligned(16))) unsigned short buf[32];
#pragma unroll
    for (int j = 0; j < 32; ++j) buf[j] = f2bf(src[(size_t)j * DOUT]);
#pragma unroll
    for (int q = 0; q < 4; ++q)
        reinterpret_cast<uint4*>(dst)[q] = reinterpret_cast<const uint4*>(buf)[q];
}

// ---------------------------------------------------------------------------
// K3: exclusive scan of 16 group counts (slot-major: g = slot*8 + expert)
// ---------------------------------------------------------------------------
__global__ void scan_kernel(const int* __restrict__ counts, int* __restrict__ offsets)
{
    if (threadIdx.x == 0 && blockIdx.x == 0) {
        int s = 0;
#pragma unroll
        for (int g = 0; g < 2 * NE; ++g) { offsets[g] = s; s += counts[g]; }
    }
}

// ---------------------------------------------------------------------------
// K4: scatter token ids + gate weights into grouped order
// ---------------------------------------------------------------------------
__global__ __launch_bounds__(256) void scatter_kernel(
    const int* __restrict__ e0a, const int* __restrict__ e1a,
    const float* __restrict__ g0a, const float* __restrict__ g1a,
    const int* __restrict__ r0a, const int* __restrict__ r1a,
    const int* __restrict__ offsets,
    int* __restrict__ perm, float* __restrict__ pgate)
{
    const int n = blockIdx.x * 256 + threadIdx.x;
    const int i0 = offsets[e0a[n]] + r0a[n];
    perm[i0] = n; pgate[i0] = g0a[n];
    const int i1 = offsets[NE + e1a[n]] + r1a[n];
    perm[i1] = n; pgate[i1] = g1a[n];
}

// ---------------------------------------------------------------------------
// K5/K6: grouped GEMM. 128x128 tile, BK=64, 4 waves (each 64x64 via 4x4
// 16x16x32 bf16 MFMA frags). A rows gathered via perm; B = WT[e] ([n][k]).
// ACCUM=0: out = g*(acc+b)  (slot 0, covers every element once)
// ACCUM=1: out += g*(acc+b) (slot 1, after pass A in stream order)
// ---------------------------------------------------------------------------
template<int ACCUM>
__global__ __launch_bounds__(256, 2) void gemm_kernel(
    const unsigned short* __restrict__ Xb,
    const unsigned short* __restrict__ WT,
    const float* __restrict__ bexp,
    const int* __restrict__ perm, const float* __restrict__ pgate,
    const int* __restrict__ counts, const int* __restrict__ offsets,
    float* __restrict__ out)
{
    constexpr int BMv = 128, BNv = 128, BKv = 64;
    __shared__ unsigned short As[BMv * BKv];   // [m][k] 16KB
    __shared__ unsigned short Bs[BNv * BKv];   // [n][k] 16KB
    __shared__ int   toks[BMv];
    __shared__ float gts[BMv];

    const int e   = blockIdx.z;
    const int g   = ACCUM ? (NE + e) : e;
    const int cnt = counts[g];
    const int mt  = blockIdx.x;
    if (mt * BMv >= cnt) return;               // block-uniform early exit
    const int start = offsets[g];
    const int valid = min(BMv, cnt - mt * BMv);
    const int tid = threadIdx.x;
    if (tid < BMv) {
        const int src = start + mt * BMv + tid;
        toks[tid] = (tid < valid) ? perm[src] : 0;
        gts[tid]  = (tid < valid) ? pgate[src] : 0.f;
    }
    __syncthreads();

    const int l = tid & 63;
    const int w = tid >> 6;
    const int srow = w * 8 + (l >> 3);         // staging row 0..31 (per issue)
    const int scol = (l & 7) * 8;              // staging k-col (bf16 elems)
    const int n0 = blockIdx.y * BNv;

    const unsigned short* asrc[4];
    const unsigned short* bsrc[4];
#pragma unroll
    for (int i = 0; i < 4; ++i) {
        asrc[i] = Xb + (size_t)toks[i * 32 + srow] * DIN + scol;
        bsrc[i] = WT + ((size_t)e * DOUT + n0 + i * 32 + srow) * DIN + scol;
    }

    f32x4 acc[4][4];
#pragma unroll
    for (int a = 0; a < 4; ++a)
#pragma unroll
        for (int b = 0; b < 4; ++b) acc[a][b] = (f32x4){0.f, 0.f, 0.f, 0.f};

    const int wm = w >> 1, wn = w & 1;         // 2x2 wave grid over 128x128
    const int fr = l & 15;                     // fragment row (A) / col-row (B)
    const int fk = (l >> 4) * 8;               // fragment k offset

    for (int k0 = 0; k0 < DIN; k0 += BKv) {
        bhalf8 ta[4], tb[4];
#pragma unroll
        for (int i = 0; i < 4; ++i) {
            ta[i] = *reinterpret_cast<const bhalf8*>(asrc[i] + k0);
            tb[i] = *reinterpret_cast<const bhalf8*>(bsrc[i] + k0);
        }
        __syncthreads();                       // prior compute done reading LDS
#pragma unroll
        for (int i = 0; i < 4; ++i) {
            *reinterpret_cast<bhalf8*>(&As[(i * 32 + srow) * BKv + scol]) = ta[i];
            *reinterpret_cast<bhalf8*>(&Bs[(i * 32 + srow) * BKv + scol]) = tb[i];
        }
        __syncthreads();                       // staging visible
#pragma unroll
        for (int ks = 0; ks < 2; ++ks) {
            bhalf8 af[4], bf[4];
#pragma unroll
            for (int fm = 0; fm < 4; ++fm)
                af[fm] = *reinterpret_cast<const bhalf8*>(
                    &As[(wm * 64 + fm * 16 + fr) * BKv + ks * 32 + fk]);
#pragma unroll
            for (int fn = 0; fn < 4; ++fn)
                bf[fn] = *reinterpret_cast<const bhalf8*>(
                    &Bs[(wn * 64 + fn * 16 + fr) * BKv + ks * 32 + fk]);
#pragma unroll
            for (int fm = 0; fm < 4; ++fm)
#pragma unroll
                for (int fn = 0; fn < 4; ++fn)
                    acc[fm][fn] = __builtin_amdgcn_mfma_f32_16x16x32_bf16(
                        af[fm], bf[fn], acc[fm][fn], 0, 0, 0);
        }
    }

    // ---- epilogue: scale by per-row gate, add gated bias, write split chunks
    size_t base; int width, cstart;
    if (n0 < 512)       { base = 0;                   width = 512; cstart = n0; }
    else if (n0 < 1024) { base = (size_t)NT * 512;    width = 512; cstart = n0 - 512; }
    else                { base = (size_t)NT * 1024;   width = 256; cstart = n0 - 1024; }
    const int lc = l & 15, lr = l >> 4;
    const int coloff = cstart + wn * 64 + lc;
    float bval[4];
#pragma unroll
    for (int fn = 0; fn < 4; ++fn)
        bval[fn] = bexp[(size_t)e * DOUT + n0 + wn * 64 + fn * 16 + lc];
#pragma unroll
    for (int fm = 0; fm < 4; ++fm) {
#pragma unroll
        for (int j = 0; j < 4; ++j) {
            const int row = wm * 64 + fm * 16 + lr * 4 + j;   // C/D: row=(l>>4)*4+j
            if (row < valid) {
                const float gg = gts[row];
                float* op = out + base + (size_t)toks[row] * width + coloff;
#pragma unroll
                for (int fn = 0; fn < 4; ++fn) {
                    const float v = gg * (acc[fm][fn][j] + bval[fn]);
                    if (ACCUM) op[fn * 16] += v; else op[fn * 16] = v;
                }
            }
        }
    }
}

// ---------------------------------------------------------------------------
// host launcher
// ---------------------------------------------------------------------------
extern "C" void kernel_launch(void* const* d_in, const int* in_sizes, int n_in,
                              void* d_out, int out_size, void* d_ws, size_t ws_size,
                              hipStream_t stream) {
    const float* x     = (const float*)d_in[0];
    const float* temb  = (const float*)d_in[1];
    const int*   atype = (const int*)d_in[2];
    const float* Wg    = (const float*)d_in[3];
    const float* Wexp  = (const float*)d_in[4];
    const float* bexp  = (const float*)d_in[5];
    float* out = (float*)d_out;
    char*  ws  = (char*)d_ws;

    // workspace layout (14,844,032 bytes total)
    unsigned short* xb = (unsigned short*)(ws);                        // 4 MB
    unsigned short* wt = (unsigned short*)(ws + (size_t)4194304);      // 10.5 MB
    char* meta = ws + (size_t)14680064;
    int*   e0a = (int*)(meta);
    int*   e1a = (int*)(meta + 16384);
    float* g0a = (float*)(meta + 32768);
    float* g1a = (float*)(meta + 49152);
    int*   r0a = (int*)(meta + 65536);
    int*   r1a = (int*)(meta + 81920);
    int*   counts  = (int*)(meta + 98304);
    int*   offsets = (int*)(meta + 98304 + 64);
    int*   perm    = (int*)(meta + 98304 + 128);
    float* pgate   = (float*)(meta + 98304 + 128 + 32768);

    hipMemsetAsync(counts, 0, 16 * sizeof(int), stream);
    gate_kernel<<<dim3(NT / 4), dim3(256), 0, stream>>>(
        x, temb, atype, Wg, xb, e0a, e1a, g0a, g1a, r0a, r1a, counts);
    convw_kernel<<<dim3(DOUT / 64, DIN / 32, NE), dim3(64), 0, stream>>>(Wexp, wt);
    scan_kernel<<<dim3(1), dim3(64), 0, stream>>>(counts, offsets);
    scatter_kernel<<<dim3(NT / 256), dim3(256), 0, stream>>>(
        e0a, e1a, g0a, g1a, r0a, r1a, offsets, perm, pgate);
    gemm_kernel<0><<<dim3(NT / 128, DOUT / 128, NE), dim3(256), 0, stream>>>(
        xb, wt, bexp, perm, pgate, counts, offsets, out);
    gemm_kernel<1><<<dim3(NT / 128, DOUT / 128, NE), dim3(256), 0, stream>>>(
        xb, wt, bexp, perm, pgate, counts, offsets, out);
}

// Round 2
// 167.347 us; speedup vs baseline: 1.5271x; 1.5271x over previous
//
#include <hip/hip_runtime.h>
#include <hip/hip_bf16.h>
#include <cstdint>
#include <cmath>

#define NT 4096      // tokens
#define DIN 512      // input dim
#define DOUT 1280    // total output dim
#define NE 8         // experts
#define TDIM 64      // type-embedding dim

typedef __attribute__((ext_vector_type(8))) short bhalf8;
typedef __attribute__((ext_vector_type(4))) float f32x4;

__device__ __forceinline__ unsigned short f2bf(float f) {
    __hip_bfloat16 h = __float2bfloat16(f);
    return *reinterpret_cast<unsigned short*>(&h);
}

// ---------------------------------------------------------------------------
// K1: gating (fp32 exact) + x -> bf16 conversion. One wave (64 lanes) / token.
// NO atomics — rank/scatter moved to sort_kernel.
// ---------------------------------------------------------------------------
__global__ __launch_bounds__(256) void gate_kernel(
    const float* __restrict__ x, const float* __restrict__ temb,
    const int* __restrict__ atype, const float* __restrict__ Wg,
    unsigned short* __restrict__ xb,
    int* __restrict__ e0a, int* __restrict__ e1a,
    float* __restrict__ g0a, float* __restrict__ g1a)
{
    const int n = blockIdx.x * 4 + (threadIdx.x >> 6);
    const int l = threadIdx.x & 63;
    float acc[NE];
#pragma unroll
    for (int e = 0; e < NE; ++e) acc[e] = 0.f;

    const float* xr = x + (size_t)n * DIN;
#pragma unroll
    for (int i = 0; i < DIN / 64; ++i) {
        const int k = i * 64 + l;
        const float xv = xr[k];
        xb[(size_t)n * DIN + k] = f2bf(xv);           // coalesced 128B/wave
        const float* wr = Wg + (size_t)k * NE;
#pragma unroll
        for (int e = 0; e < NE; ++e) acc[e] = fmaf(xv, wr[e], acc[e]);
    }
    {   // tebd part: lane l covers tebd dim l (TDIM == 64)
        const int t = atype[n];
        const float tv = temb[(size_t)t * TDIM + l];
        const float* wr = Wg + (size_t)(DIN + l) * NE;
#pragma unroll
        for (int e = 0; e < NE; ++e) acc[e] = fmaf(tv, wr[e], acc[e]);
    }
    // wave butterfly reduce (all lanes end with full sums)
#pragma unroll
    for (int off = 32; off > 0; off >>= 1) {
#pragma unroll
        for (int e = 0; e < NE; ++e) acc[e] += __shfl_xor(acc[e], off, 64);
    }
    if (l == 0) {
        // top-2, lowest-index-wins on exact ties (matches jax.lax.top_k)
        int e0 = 0; float v0 = acc[0];
#pragma unroll
        for (int e = 1; e < NE; ++e) if (acc[e] > v0) { v0 = acc[e]; e0 = e; }
        int e1 = -1; float v1 = -INFINITY;
#pragma unroll
        for (int e = 0; e < NE; ++e) {
            if (e == e0) continue;
            if (acc[e] > v1) { v1 = acc[e]; e1 = e; }
        }
        const float p1 = expf(v1 - v0);        // softmax over [v0, v1], v0 = max
        const float s  = 1.f + p1;
        e0a[n] = e0; e1a[n] = e1; g0a[n] = 1.f / s; g1a[n] = p1 / s;
    }
}

// ---------------------------------------------------------------------------
// K2: W_exp [e][k][n] f32 -> WT [e][n][k] bf16 (convert + transpose).
// ---------------------------------------------------------------------------
__global__ __launch_bounds__(64) void convw_kernel(
    const float* __restrict__ W, unsigned short* __restrict__ WT)
{
    const int n  = blockIdx.x * 64 + threadIdx.x;   // 0..1279
    const int k0 = blockIdx.y * 32;                 // 0..480
    const int e  = blockIdx.z;
    const float* src = W + ((size_t)e * DIN + k0) * DOUT + n;
    unsigned short* dst = WT + ((size_t)e * DOUT + n) * DIN + k0;
    __attribute__((aligned(16))) unsigned short buf[32];
#pragma unroll
    for (int j = 0; j < 32; ++j) buf[j] = f2bf(src[(size_t)j * DOUT]);
#pragma unroll
    for (int q = 0; q < 4; ++q)
        reinterpret_cast<uint4*>(dst)[q] = reinterpret_cast<const uint4*>(buf)[q];
}

// ---------------------------------------------------------------------------
// K3: single-block counting sort. 1024 threads, each owns 4 tokens (8 entries).
// hist[g][t] layout: runtime-g LDS indexing is bank-conflict-free (bank=t%32).
// Produces perm/pgate (grouped, slot-major g = slot*8+e), counts, offsets.
// Deterministic; no global atomics.
// ---------------------------------------------------------------------------
#define SORT_T 1024
__global__ __launch_bounds__(1024) void sort_kernel(
    const int* __restrict__ e0a, const int* __restrict__ e1a,
    const float* __restrict__ g0a, const float* __restrict__ g1a,
    int* __restrict__ counts, int* __restrict__ offsets,
    int* __restrict__ perm, float* __restrict__ pgate)
{
    __shared__ int hist[16 * SORT_T];     // 64 KB
    __shared__ int gtot[16], gbase[16];
    const int t = threadIdx.x;
#pragma unroll
    for (int g = 0; g < 16; ++g) hist[g * SORT_T + t] = 0;
    __syncthreads();

    const int nbase = t * 4;
    int keys[8];
#pragma unroll
    for (int i = 0; i < 4; ++i) {
        const int n = nbase + i;
        keys[2 * i]     = e0a[n];          // slot-0 group = e0
        keys[2 * i + 1] = 8 + e1a[n];      // slot-1 group = 8 + e1
    }
#pragma unroll
    for (int i = 0; i < 8; ++i) hist[keys[i] * SORT_T + t] += 1;
    __syncthreads();

    // per-group exclusive scan over t: wave w handles group w (16 waves)
    const int w = t >> 6, l = t & 63;
    {
        int running = 0;
        for (int c = 0; c < SORT_T / 64; ++c) {
            int v = hist[w * SORT_T + c * 64 + l];
            int inc = v;
#pragma unroll
            for (int d = 1; d < 64; d <<= 1) {
                int u = __shfl_up(inc, d, 64);
                if (l >= d) inc += u;
            }
            hist[w * SORT_T + c * 64 + l] = running + inc - v;   // exclusive
            running += __shfl(inc, 63, 64);
        }
        if (l == 0) gtot[w] = running;
    }
    __syncthreads();
    if (t == 0) {
        int s = 0;
#pragma unroll
        for (int g = 0; g < 16; ++g) {
            gbase[g] = s; offsets[g] = s; counts[g] = gtot[g]; s += gtot[g];
        }
    }
    __syncthreads();

    // scatter (stable within thread via post-increment of own hist cell)
#pragma unroll
    for (int i = 0; i < 4; ++i) {
        const int n = nbase + i;
        {
            const int k = keys[2 * i];
            const int pos = gbase[k] + hist[k * SORT_T + t]++;
            perm[pos] = n; pgate[pos] = g0a[n];
        }
        {
            const int k = keys[2 * i + 1];
            const int pos = gbase[k] + hist[k * SORT_T + t]++;
            perm[pos] = n; pgate[pos] = g1a[n];
        }
    }
}

// ---------------------------------------------------------------------------
// K4/K5: grouped GEMM. 128x128 tile, BK=64, 4 waves (each 64x64 via 4x4
// 16x16x32 bf16 MFMA frags). A rows gathered via perm; B = WT[e] ([n][k]).
// ACCUM=0: out = g*(acc+b)  (slot 0, covers every element once)
// ACCUM=1: out += g*(acc+b) (slot 1, after pass A in stream order)
// ---------------------------------------------------------------------------
template<int ACCUM>
__global__ __launch_bounds__(256, 2) void gemm_kernel(
    const unsigned short* __restrict__ Xb,
    const unsigned short* __restrict__ WT,
    const float* __restrict__ bexp,
    const int* __restrict__ perm, const float* __restrict__ pgate,
    const int* __restrict__ counts, const int* __restrict__ offsets,
    float* __restrict__ out)
{
    constexpr int BMv = 128, BNv = 128, BKv = 64;
    __shared__ unsigned short As[BMv * BKv];   // [m][k] 16KB
    __shared__ unsigned short Bs[BNv * BKv];   // [n][k] 16KB
    __shared__ int   toks[BMv];
    __shared__ float gts[BMv];

    const int e   = blockIdx.z;
    const int g   = ACCUM ? (NE + e) : e;
    const int cnt = counts[g];
    const int mt  = blockIdx.x;
    if (mt * BMv >= cnt) return;               // block-uniform early exit
    const int start = offsets[g];
    const int valid = min(BMv, cnt - mt * BMv);
    const int tid = threadIdx.x;
    if (tid < BMv) {
        const int src = start + mt * BMv + tid;
        toks[tid] = (tid < valid) ? perm[src] : 0;
        gts[tid]  = (tid < valid) ? pgate[src] : 0.f;
    }
    __syncthreads();

    const int l = tid & 63;
    const int w = tid >> 6;
    const int srow = w * 8 + (l >> 3);         // staging row 0..31 (per issue)
    const int scol = (l & 7) * 8;              // staging k-col (bf16 elems)
    const int n0 = blockIdx.y * BNv;

    const unsigned short* asrc[4];
    const unsigned short* bsrc[4];
#pragma unroll
    for (int i = 0; i < 4; ++i) {
        asrc[i] = Xb + (size_t)toks[i * 32 + srow] * DIN + scol;
        bsrc[i] = WT + ((size_t)e * DOUT + n0 + i * 32 + srow) * DIN + scol;
    }

    f32x4 acc[4][4];
#pragma unroll
    for (int a = 0; a < 4; ++a)
#pragma unroll
        for (int b = 0; b < 4; ++b) acc[a][b] = (f32x4){0.f, 0.f, 0.f, 0.f};

    const int wm = w >> 1, wn = w & 1;         // 2x2 wave grid over 128x128
    const int fr = l & 15;                     // fragment row (A) / col-row (B)
    const int fk = (l >> 4) * 8;               // fragment k offset

    for (int k0 = 0; k0 < DIN; k0 += BKv) {
        bhalf8 ta[4], tb[4];
#pragma unroll
        for (int i = 0; i < 4; ++i) {
            ta[i] = *reinterpret_cast<const bhalf8*>(asrc[i] + k0);
            tb[i] = *reinterpret_cast<const bhalf8*>(bsrc[i] + k0);
        }
        __syncthreads();                       // prior compute done reading LDS
#pragma unroll
        for (int i = 0; i < 4; ++i) {
            *reinterpret_cast<bhalf8*>(&As[(i * 32 + srow) * BKv + scol]) = ta[i];
            *reinterpret_cast<bhalf8*>(&Bs[(i * 32 + srow) * BKv + scol]) = tb[i];
        }
        __syncthreads();                       // staging visible
#pragma unroll
        for (int ks = 0; ks < 2; ++ks) {
            bhalf8 af[4], bf[4];
#pragma unroll
            for (int fm = 0; fm < 4; ++fm)
                af[fm] = *reinterpret_cast<const bhalf8*>(
                    &As[(wm * 64 + fm * 16 + fr) * BKv + ks * 32 + fk]);
#pragma unroll
            for (int fn = 0; fn < 4; ++fn)
                bf[fn] = *reinterpret_cast<const bhalf8*>(
                    &Bs[(wn * 64 + fn * 16 + fr) * BKv + ks * 32 + fk]);
#pragma unroll
            for (int fm = 0; fm < 4; ++fm)
#pragma unroll
                for (int fn = 0; fn < 4; ++fn)
                    acc[fm][fn] = __builtin_amdgcn_mfma_f32_16x16x32_bf16(
                        af[fm], bf[fn], acc[fm][fn], 0, 0, 0);
        }
    }

    // ---- epilogue: scale by per-row gate, add gated bias, write split chunks
    size_t base; int width, cstart;
    if (n0 < 512)       { base = 0;                   width = 512; cstart = n0; }
    else if (n0 < 1024) { base = (size_t)NT * 512;    width = 512; cstart = n0 - 512; }
    else                { base = (size_t)NT * 1024;   width = 256; cstart = n0 - 1024; }
    const int lc = l & 15, lr = l >> 4;
    const int coloff = cstart + wn * 64 + lc;
    float bval[4];
#pragma unroll
    for (int fn = 0; fn < 4; ++fn)
        bval[fn] = bexp[(size_t)e * DOUT + n0 + wn * 64 + fn * 16 + lc];
#pragma unroll
    for (int fm = 0; fm < 4; ++fm) {
#pragma unroll
        for (int j = 0; j < 4; ++j) {
            const int row = wm * 64 + fm * 16 + lr * 4 + j;   // C/D: row=(l>>4)*4+j
            if (row < valid) {
                const float gg = gts[row];
                float* op = out + base + (size_t)toks[row] * width + coloff;
#pragma unroll
                for (int fn = 0; fn < 4; ++fn) {
                    const float v = gg * (acc[fm][fn][j] + bval[fn]);
                    if (ACCUM) op[fn * 16] += v; else op[fn * 16] = v;
                }
            }
        }
    }
}

// ---------------------------------------------------------------------------
// host launcher
// ---------------------------------------------------------------------------
extern "C" void kernel_launch(void* const* d_in, const int* in_sizes, int n_in,
                              void* d_out, int out_size, void* d_ws, size_t ws_size,
                              hipStream_t stream) {
    const float* x     = (const float*)d_in[0];
    const float* temb  = (const float*)d_in[1];
    const int*   atype = (const int*)d_in[2];
    const float* Wg    = (const float*)d_in[3];
    const float* Wexp  = (const float*)d_in[4];
    const float* bexp  = (const float*)d_in[5];
    float* out = (float*)d_out;
    char*  ws  = (char*)d_ws;

    // workspace layout
    unsigned short* xb = (unsigned short*)(ws);                        // 4 MB
    unsigned short* wt = (unsigned short*)(ws + (size_t)4194304);      // 10.5 MB
    char* meta = ws + (size_t)14680064;
    int*   e0a = (int*)(meta);
    int*   e1a = (int*)(meta + 16384);
    float* g0a = (float*)(meta + 32768);
    float* g1a = (float*)(meta + 49152);
    int*   perm    = (int*)(meta + 65536);
    float* pgate   = (float*)(meta + 65536 + 32768);
    int*   counts  = (int*)(meta + 131072);
    int*   offsets = (int*)(meta + 131072 + 64);

    gate_kernel<<<dim3(NT / 4), dim3(256), 0, stream>>>(
        x, temb, atype, Wg, xb, e0a, e1a, g0a, g1a);
    convw_kernel<<<dim3(DOUT / 64, DIN / 32, NE), dim3(64), 0, stream>>>(Wexp, wt);
    sort_kernel<<<dim3(1), dim3(1024), 0, stream>>>(
        e0a, e1a, g0a, g1a, counts, offsets, perm, pgate);
    gemm_kernel<0><<<dim3(NT / 128, DOUT / 128, NE), dim3(256), 0, stream>>>(
        xb, wt, bexp, perm, pgate, counts, offsets, out);
    gemm_kernel<1><<<dim3(NT / 128, DOUT / 128, NE), dim3(256), 0, stream>>>(
        xb, wt, bexp, perm, pgate, counts, offsets, out);
}

// Round 3
// 101.754 us; speedup vs baseline: 2.5114x; 1.6446x over previous
//
#include <hip/hip_runtime.h>
#include <hip/hip_bf16.h>
#include <cstdint>
#include <cmath>

#define NT 4096      // tokens
#define DIN 512      // input dim
#define DOUT 1280    // total output dim
#define NE 8         // experts
#define TDIM 64      // type-embedding dim
#define MAXTILES 80  // sum_g ceil(cnt_g/128) <= 4096*2/128 + 16 = 80

typedef __attribute__((ext_vector_type(8))) short bhalf8;
typedef __attribute__((ext_vector_type(4))) float f32x4;

__device__ __forceinline__ unsigned short f2bf(float f) {
    __hip_bfloat16 h = __float2bfloat16(f);
    return *reinterpret_cast<unsigned short*>(&h);
}

// HW f32 global atomic add (no CAS loop, no return). addr first, data second.
__device__ __forceinline__ void gatomic_fadd(float* p, float v) {
    asm volatile("global_atomic_add_f32 %0, %1, off" : : "v"(p), "v"(v) : "memory");
}

// ---------------------------------------------------------------------------
// K1: gating (fp32 exact) + x -> bf16 conversion. One wave / token. No atomics.
// ---------------------------------------------------------------------------
__global__ __launch_bounds__(256) void gate_kernel(
    const float* __restrict__ x, const float* __restrict__ temb,
    const int* __restrict__ atype, const float* __restrict__ Wg,
    unsigned short* __restrict__ xb,
    int* __restrict__ e0a, int* __restrict__ e1a,
    float* __restrict__ g0a, float* __restrict__ g1a)
{
    const int n = blockIdx.x * 4 + (threadIdx.x >> 6);
    const int l = threadIdx.x & 63;
    float acc[NE];
#pragma unroll
    for (int e = 0; e < NE; ++e) acc[e] = 0.f;

    const float* xr = x + (size_t)n * DIN;
#pragma unroll
    for (int i = 0; i < DIN / 64; ++i) {
        const int k = i * 64 + l;
        const float xv = xr[k];
        xb[(size_t)n * DIN + k] = f2bf(xv);
        const float* wr = Wg + (size_t)k * NE;
#pragma unroll
        for (int e = 0; e < NE; ++e) acc[e] = fmaf(xv, wr[e], acc[e]);
    }
    {   // tebd: lane l covers tebd dim l (TDIM == 64)
        const int t = atype[n];
        const float tv = temb[(size_t)t * TDIM + l];
        const float* wr = Wg + (size_t)(DIN + l) * NE;
#pragma unroll
        for (int e = 0; e < NE; ++e) acc[e] = fmaf(tv, wr[e], acc[e]);
    }
#pragma unroll
    for (int off = 32; off > 0; off >>= 1) {
#pragma unroll
        for (int e = 0; e < NE; ++e) acc[e] += __shfl_xor(acc[e], off, 64);
    }
    if (l == 0) {
        int e0 = 0; float v0 = acc[0];
#pragma unroll
        for (int e = 1; e < NE; ++e) if (acc[e] > v0) { v0 = acc[e]; e0 = e; }
        int e1 = -1; float v1 = -INFINITY;
#pragma unroll
        for (int e = 0; e < NE; ++e) {
            if (e == e0) continue;
            if (acc[e] > v1) { v1 = acc[e]; e1 = e; }
        }
        const float p1 = expf(v1 - v0);
        const float s  = 1.f + p1;
        e0a[n] = e0; e1a[n] = e1; g0a[n] = 1.f / s; g1a[n] = p1 / s;
    }
}

// ---------------------------------------------------------------------------
// K2: W_exp [e][k][n] f32 -> WT [e][n][k] bf16 (convert + transpose).
// ---------------------------------------------------------------------------
__global__ __launch_bounds__(64) void convw_kernel(
    const float* __restrict__ W, unsigned short* __restrict__ WT)
{
    const int n  = blockIdx.x * 64 + threadIdx.x;
    const int k0 = blockIdx.y * 32;
    const int e  = blockIdx.z;
    const float* src = W + ((size_t)e * DIN + k0) * DOUT + n;
    unsigned short* dst = WT + ((size_t)e * DOUT + n) * DIN + k0;
    __attribute__((aligned(16))) unsigned short buf[32];
#pragma unroll
    for (int j = 0; j < 32; ++j) buf[j] = f2bf(src[(size_t)j * DOUT]);
#pragma unroll
    for (int q = 0; q < 4; ++q)
        reinterpret_cast<uint4*>(dst)[q] = reinterpret_cast<const uint4*>(buf)[q];
}

// ---------------------------------------------------------------------------
// K3: single-block counting sort -> PADDED grouped layout.
// Each group padded to a multiple of 128 (dummies: token 0, gate 0), so tile t
// is exactly perm[t*128 .. t*128+128) with a single expert tile_expert[t].
// ---------------------------------------------------------------------------
#define SORT_T 1024
__global__ __launch_bounds__(1024) void sort_kernel(
    const int* __restrict__ e0a, const int* __restrict__ e1a,
    const float* __restrict__ g0a, const float* __restrict__ g1a,
    int* __restrict__ perm, float* __restrict__ pgate,
    int* __restrict__ tile_expert, int* __restrict__ ntiles_out)
{
    __shared__ int hist[16 * SORT_T];     // 64 KB
    __shared__ int gtot[16], gbase[16];
    const int t = threadIdx.x;
    for (int i = t; i < MAXTILES * 128; i += SORT_T) { perm[i] = 0; pgate[i] = 0.f; }
#pragma unroll
    for (int g = 0; g < 16; ++g) hist[g * SORT_T + t] = 0;
    __syncthreads();

    const int nbase = t * 4;
    int keys[8];
#pragma unroll
    for (int i = 0; i < 4; ++i) {
        const int n = nbase + i;
        keys[2 * i]     = e0a[n];
        keys[2 * i + 1] = 8 + e1a[n];
    }
#pragma unroll
    for (int i = 0; i < 8; ++i) hist[keys[i] * SORT_T + t] += 1;
    __syncthreads();

    // per-group exclusive scan over thread index: wave w owns group w
    const int w = t >> 6, l = t & 63;
    {
        int running = 0;
        for (int c = 0; c < SORT_T / 64; ++c) {
            int v = hist[w * SORT_T + c * 64 + l];
            int inc = v;
#pragma unroll
            for (int d = 1; d < 64; d <<= 1) {
                int u = __shfl_up(inc, d, 64);
                if (l >= d) inc += u;
            }
            hist[w * SORT_T + c * 64 + l] = running + inc - v;
            running += __shfl(inc, 63, 64);
        }
        if (l == 0) gtot[w] = running;
    }
    __syncthreads();
    if (t == 0) {
        int s = 0;
#pragma unroll
        for (int g = 0; g < 16; ++g) {
            gbase[g] = s;
            const int ntg = (gtot[g] + 127) >> 7;       // tiles for group g
            for (int k = 0; k < ntg; ++k) tile_expert[s / 128 + k] = g & 7;
            s += ntg * 128;                             // padded advance
        }
        *ntiles_out = s / 128;
    }
    __syncthreads();

#pragma unroll
    for (int i = 0; i < 4; ++i) {
        const int n = nbase + i;
        {
            const int k = keys[2 * i];
            const int pos = gbase[k] + hist[k * SORT_T + t]++;
            perm[pos] = n; pgate[pos] = g0a[n];
        }
        {
            const int k = keys[2 * i + 1];
            const int pos = gbase[k] + hist[k * SORT_T + t]++;
            perm[pos] = n; pgate[pos] = g1a[n];
        }
    }
}

// ---------------------------------------------------------------------------
// K4: single grouped GEMM over all padded tiles. 128x128 tile, BK=64, 4 waves.
// LDS XOR-swizzled (chunk ^= row&7, both write & read) -> conflict-free.
// Software-pipelined staging. Epilogue: HW f32 atomicAdd onto zeroed out
// (each element gets exactly 2 adds -> order-independent, deterministic).
// ---------------------------------------------------------------------------
__device__ __forceinline__ int swz(int row, int chunk) {
    return row * 64 + ((chunk ^ (row & 7)) << 3);       // elem index, 16B chunks
}

__global__ __launch_bounds__(256, 2) void gemm_kernel(
    const unsigned short* __restrict__ Xb,
    const unsigned short* __restrict__ WT,
    const float* __restrict__ bexp,
    const int* __restrict__ perm, const float* __restrict__ pgate,
    const int* __restrict__ tile_expert, const int* __restrict__ ntiles_ptr,
    float* __restrict__ out)
{
    constexpr int BKv = 64;
    if ((int)blockIdx.x >= *ntiles_ptr) return;         // block-uniform
    const int e = tile_expert[blockIdx.x];

    __shared__ unsigned short As[128 * BKv];            // 16KB (swizzled)
    __shared__ unsigned short Bs[128 * BKv];            // 16KB (swizzled)
    __shared__ int   toks[128];
    __shared__ float gts[128];

    const int tid = threadIdx.x;
    if (tid < 128) {
        toks[tid] = perm[blockIdx.x * 128 + tid];
        gts[tid]  = pgate[blockIdx.x * 128 + tid];
    }
    __syncthreads();

    const int l = tid & 63;
    const int w = tid >> 6;
    const int srow = w * 8 + (l >> 3);                  // + i*32 -> rows
    const int schk = l & 7;                             // 16B chunk in row
    const int n0 = blockIdx.y * 128;

    const unsigned short* asrc[4];
    const unsigned short* bsrc[4];
#pragma unroll
    for (int i = 0; i < 4; ++i) {
        asrc[i] = Xb + (size_t)toks[i * 32 + srow] * DIN + schk * 8;
        bsrc[i] = WT + ((size_t)e * DOUT + n0 + i * 32 + srow) * DIN + schk * 8;
    }

    f32x4 acc[4][4];
#pragma unroll
    for (int a = 0; a < 4; ++a)
#pragma unroll
        for (int b = 0; b < 4; ++b) acc[a][b] = (f32x4){0.f, 0.f, 0.f, 0.f};

    const int wm = w >> 1, wn = w & 1;
    const int fr = l & 15;                              // fragment row
    const int fh = l >> 4;                              // k-chunk within half

    bhalf8 ta[4], tb[4];
#pragma unroll
    for (int i = 0; i < 4; ++i) {                       // prologue loads (k0=0)
        ta[i] = *reinterpret_cast<const bhalf8*>(asrc[i]);
        tb[i] = *reinterpret_cast<const bhalf8*>(bsrc[i]);
    }

    for (int k0 = 0; k0 < DIN; k0 += BKv) {
        __syncthreads();                                // prev compute done
#pragma unroll
        for (int i = 0; i < 4; ++i) {
            const int row = i * 32 + srow;
            *reinterpret_cast<bhalf8*>(&As[swz(row, schk)]) = ta[i];
            *reinterpret_cast<bhalf8*>(&Bs[swz(row, schk)]) = tb[i];
        }
        __syncthreads();                                // staging visible
        if (k0 + BKv < DIN) {                           // prefetch next K-tile
#pragma unroll
            for (int i = 0; i < 4; ++i) {
                ta[i] = *reinterpret_cast<const bhalf8*>(asrc[i] + k0 + BKv);
                tb[i] = *reinterpret_cast<const bhalf8*>(bsrc[i] + k0 + BKv);
            }
        }
#pragma unroll
        for (int ks = 0; ks < 2; ++ks) {
            bhalf8 af[4], bff[4];
#pragma unroll
            for (int fm = 0; fm < 4; ++fm)
                af[fm] = *reinterpret_cast<const bhalf8*>(
                    &As[swz(wm * 64 + fm * 16 + fr, ks * 4 + fh)]);
#pragma unroll
            for (int fn = 0; fn < 4; ++fn)
                bff[fn] = *reinterpret_cast<const bhalf8*>(
                    &Bs[swz(wn * 64 + fn * 16 + fr, ks * 4 + fh)]);
#pragma unroll
            for (int fm = 0; fm < 4; ++fm)
#pragma unroll
                for (int fn = 0; fn < 4; ++fn)
                    acc[fm][fn] = __builtin_amdgcn_mfma_f32_16x16x32_bf16(
                        af[fm], bff[fn], acc[fm][fn], 0, 0, 0);
        }
    }

    // ---- epilogue: atomic accumulate g*(acc+bias) into split output chunks
    size_t base; int width, cstart;
    if (n0 < 512)       { base = 0;                 width = 512; cstart = n0; }
    else if (n0 < 1024) { base = (size_t)NT * 512;  width = 512; cstart = n0 - 512; }
    else                { base = (size_t)NT * 1024; width = 256; cstart = n0 - 1024; }
    const int lc = l & 15, lr = l >> 4;
    const int coloff = cstart + wn * 64 + lc;
    float bval[4];
#pragma unroll
    for (int fn = 0; fn < 4; ++fn)
        bval[fn] = bexp[(size_t)e * DOUT + n0 + wn * 64 + fn * 16 + lc];
#pragma unroll
    for (int fm = 0; fm < 4; ++fm) {
#pragma unroll
        for (int j = 0; j < 4; ++j) {
            const int row = wm * 64 + fm * 16 + lr * 4 + j;
            const float gg = gts[row];
            if (gg != 0.f) {                            // skip dummy rows
                float* op = out + base + (size_t)toks[row] * width + coloff;
#pragma unroll
                for (int fn = 0; fn < 4; ++fn)
                    gatomic_fadd(op + fn * 16, gg * (acc[fm][fn][j] + bval[fn]));
            }
        }
    }
}

// ---------------------------------------------------------------------------
// host launcher
// ---------------------------------------------------------------------------
extern "C" void kernel_launch(void* const* d_in, const int* in_sizes, int n_in,
                              void* d_out, int out_size, void* d_ws, size_t ws_size,
                              hipStream_t stream) {
    const float* x     = (const float*)d_in[0];
    const float* temb  = (const float*)d_in[1];
    const int*   atype = (const int*)d_in[2];
    const float* Wg    = (const float*)d_in[3];
    const float* Wexp  = (const float*)d_in[4];
    const float* bexp  = (const float*)d_in[5];
    float* out = (float*)d_out;
    char*  ws  = (char*)d_ws;

    // workspace layout (~14.83 MB total)
    unsigned short* xb = (unsigned short*)(ws);                        // 4 MB
    unsigned short* wt = (unsigned short*)(ws + (size_t)4194304);      // 10.5 MB
    char* meta = ws + (size_t)14680064;
    int*   e0a = (int*)(meta);                    // 16 KB
    int*   e1a = (int*)(meta + 16384);
    float* g0a = (float*)(meta + 32768);
    float* g1a = (float*)(meta + 49152);
    int*   perm        = (int*)(meta + 65536);    // 40960 B (80*128*4)
    float* pgate       = (float*)(meta + 106496); // 40960 B
    int*   tile_expert = (int*)(meta + 147456);   // 320 B
    int*   ntiles      = (int*)(meta + 147968);   // 4 B

    hipMemsetAsync(out, 0, (size_t)out_size * sizeof(float), stream);
    gate_kernel<<<dim3(NT / 4), dim3(256), 0, stream>>>(
        x, temb, atype, Wg, xb, e0a, e1a, g0a, g1a);
    convw_kernel<<<dim3(DOUT / 64, DIN / 32, NE), dim3(64), 0, stream>>>(Wexp, wt);
    sort_kernel<<<dim3(1), dim3(SORT_T), 0, stream>>>(
        e0a, e1a, g0a, g1a, perm, pgate, tile_expert, ntiles);
    gemm_kernel<<<dim3(MAXTILES, DOUT / 128), dim3(256), 0, stream>>>(
        xb, wt, bexp, perm, pgate, tile_expert, ntiles, out);
}

// Round 4
// 93.217 us; speedup vs baseline: 2.7415x; 1.0916x over previous
//
#include <hip/hip_runtime.h>
#include <hip/hip_bf16.h>
#include <cstdint>
#include <cmath>

#define NT 4096      // tokens
#define DIN 512      // input dim
#define DOUT 1280    // total output dim
#define NE 8         // experts
#define TDIM 64      // type-embedding dim
#define MAXTILES 80  // sum_g ceil(cnt_g/128) <= 4096*2/128 + 16 = 80
#define NB 20        // DOUT / 64 n-blocks

typedef __attribute__((ext_vector_type(8))) short bhalf8;
typedef __attribute__((ext_vector_type(4))) float f32x4;

__device__ __forceinline__ unsigned short f2bf(float f) {
    __hip_bfloat16 h = __float2bfloat16(f);
    return *reinterpret_cast<unsigned short*>(&h);
}

// HW f32 global atomic add (no CAS loop, no return).
__device__ __forceinline__ void gatomic_fadd(float* p, float v) {
    asm volatile("global_atomic_add_f32 %0, %1, off" : : "v"(p), "v"(v) : "memory");
}

// async global->LDS, 16B per lane. LDS dest = wave-uniform base + lane*16.
__device__ __forceinline__ void glds16(const unsigned short* g, unsigned short* l) {
    __builtin_amdgcn_global_load_lds(
        (const __attribute__((address_space(1))) void*)g,
        (__attribute__((address_space(3))) void*)l, 16, 0, 0);
}

// ---------------------------------------------------------------------------
// K1: gating (fp32 exact) + x -> bf16 conversion. One wave / token. No atomics.
// ---------------------------------------------------------------------------
__global__ __launch_bounds__(256) void gate_kernel(
    const float* __restrict__ x, const float* __restrict__ temb,
    const int* __restrict__ atype, const float* __restrict__ Wg,
    unsigned short* __restrict__ xb,
    int* __restrict__ e0a, int* __restrict__ e1a,
    float* __restrict__ g0a, float* __restrict__ g1a)
{
    const int n = blockIdx.x * 4 + (threadIdx.x >> 6);
    const int l = threadIdx.x & 63;
    float acc[NE];
#pragma unroll
    for (int e = 0; e < NE; ++e) acc[e] = 0.f;

    const float* xr = x + (size_t)n * DIN;
#pragma unroll
    for (int i = 0; i < DIN / 64; ++i) {
        const int k = i * 64 + l;
        const float xv = xr[k];
        xb[(size_t)n * DIN + k] = f2bf(xv);
        const float* wr = Wg + (size_t)k * NE;
#pragma unroll
        for (int e = 0; e < NE; ++e) acc[e] = fmaf(xv, wr[e], acc[e]);
    }
    {   // tebd: lane l covers tebd dim l (TDIM == 64)
        const int t = atype[n];
        const float tv = temb[(size_t)t * TDIM + l];
        const float* wr = Wg + (size_t)(DIN + l) * NE;
#pragma unroll
        for (int e = 0; e < NE; ++e) acc[e] = fmaf(tv, wr[e], acc[e]);
    }
#pragma unroll
    for (int off = 32; off > 0; off >>= 1) {
#pragma unroll
        for (int e = 0; e < NE; ++e) acc[e] += __shfl_xor(acc[e], off, 64);
    }
    if (l == 0) {
        int e0 = 0; float v0 = acc[0];
#pragma unroll
        for (int e = 1; e < NE; ++e) if (acc[e] > v0) { v0 = acc[e]; e0 = e; }
        int e1 = -1; float v1 = -INFINITY;
#pragma unroll
        for (int e = 0; e < NE; ++e) {
            if (e == e0) continue;
            if (acc[e] > v1) { v1 = acc[e]; e1 = e; }
        }
        const float p1 = expf(v1 - v0);
        const float s  = 1.f + p1;
        e0a[n] = e0; e1a[n] = e1; g0a[n] = 1.f / s; g1a[n] = p1 / s;
    }
}

// ---------------------------------------------------------------------------
// K2: W_exp [e][k][n] f32 -> WT [e][n][k] bf16 (convert + transpose).
// ---------------------------------------------------------------------------
__global__ __launch_bounds__(64) void convw_kernel(
    const float* __restrict__ W, unsigned short* __restrict__ WT)
{
    const int n  = blockIdx.x * 64 + threadIdx.x;
    const int k0 = blockIdx.y * 32;
    const int e  = blockIdx.z;
    const float* src = W + ((size_t)e * DIN + k0) * DOUT + n;
    unsigned short* dst = WT + ((size_t)e * DOUT + n) * DIN + k0;
    __attribute__((aligned(16))) unsigned short buf[32];
#pragma unroll
    for (int j = 0; j < 32; ++j) buf[j] = f2bf(src[(size_t)j * DOUT]);
#pragma unroll
    for (int q = 0; q < 4; ++q)
        reinterpret_cast<uint4*>(dst)[q] = reinterpret_cast<const uint4*>(buf)[q];
}

// ---------------------------------------------------------------------------
// K3: single-block counting sort -> PADDED grouped layout (tiles of 128).
// ---------------------------------------------------------------------------
#define SORT_T 1024
__global__ __launch_bounds__(1024) void sort_kernel(
    const int* __restrict__ e0a, const int* __restrict__ e1a,
    const float* __restrict__ g0a, const float* __restrict__ g1a,
    int* __restrict__ perm, float* __restrict__ pgate,
    int* __restrict__ tile_expert, int* __restrict__ ntiles_out)
{
    __shared__ int hist[16 * SORT_T];     // 64 KB
    __shared__ int gtot[16], gbase[16];
    const int t = threadIdx.x;
    for (int i = t; i < MAXTILES * 128; i += SORT_T) { perm[i] = 0; pgate[i] = 0.f; }
#pragma unroll
    for (int g = 0; g < 16; ++g) hist[g * SORT_T + t] = 0;
    __syncthreads();

    const int nbase = t * 4;
    int keys[8];
#pragma unroll
    for (int i = 0; i < 4; ++i) {
        const int n = nbase + i;
        keys[2 * i]     = e0a[n];
        keys[2 * i + 1] = 8 + e1a[n];
    }
#pragma unroll
    for (int i = 0; i < 8; ++i) hist[keys[i] * SORT_T + t] += 1;
    __syncthreads();

    const int w = t >> 6, l = t & 63;
    {
        int running = 0;
        for (int c = 0; c < SORT_T / 64; ++c) {
            int v = hist[w * SORT_T + c * 64 + l];
            int inc = v;
#pragma unroll
            for (int d = 1; d < 64; d <<= 1) {
                int u = __shfl_up(inc, d, 64);
                if (l >= d) inc += u;
            }
            hist[w * SORT_T + c * 64 + l] = running + inc - v;
            running += __shfl(inc, 63, 64);
        }
        if (l == 0) gtot[w] = running;
    }
    __syncthreads();
    if (t == 0) {
        int s = 0;
#pragma unroll
        for (int g = 0; g < 16; ++g) {
            gbase[g] = s;
            const int ntg = (gtot[g] + 127) >> 7;
            for (int k = 0; k < ntg; ++k) tile_expert[s / 128 + k] = g & 7;
            s += ntg * 128;
        }
        *ntiles_out = s / 128;
    }
    __syncthreads();

#pragma unroll
    for (int i = 0; i < 4; ++i) {
        const int n = nbase + i;
        {
            const int k = keys[2 * i];
            const int pos = gbase[k] + hist[k * SORT_T + t]++;
            perm[pos] = n; pgate[pos] = g0a[n];
        }
        {
            const int k = keys[2 * i + 1];
            const int pos = gbase[k] + hist[k * SORT_T + t]++;
            perm[pos] = n; pgate[pos] = g1a[n];
        }
    }
}

// ---------------------------------------------------------------------------
// K4: grouped GEMM, 128x64 tile, BK=64, 4 waves (2x2, each 64x32 = 4x2 frags).
// global_load_lds staging (linear LDS dest, XOR-swizzle applied to per-lane
// GLOBAL source; reads use matching swizzle -> conflict-free).
// 1-D grid, XCD-chunked swizzle, tile-major. Atomic f32 epilogue.
// ---------------------------------------------------------------------------
__device__ __forceinline__ int swz(int row, int chunk) {
    return row * 64 + ((chunk ^ (row & 7)) << 3);       // elem idx, 16B chunks
}

__global__ __launch_bounds__(256, 4) void gemm_kernel(
    const unsigned short* __restrict__ Xb,
    const unsigned short* __restrict__ WT,
    const float* __restrict__ bexp,
    const int* __restrict__ perm, const float* __restrict__ pgate,
    const int* __restrict__ tile_expert, const int* __restrict__ ntiles_ptr,
    float* __restrict__ out)
{
    // XCD-chunked bijective swizzle over nwg = MAXTILES*NB (divisible by 8)
    constexpr int NWG = MAXTILES * NB, CPX = NWG / 8;
    const int gid = blockIdx.x;
    const int wid = (gid & 7) * CPX + (gid >> 3);
    const int tile = wid / NB, nb = wid % NB;
    if (tile >= *ntiles_ptr) return;
    const int e  = tile_expert[tile];
    const int n0 = nb * 64;

    __shared__ unsigned short As[128 * 64];   // 16 KB
    __shared__ unsigned short Bs[64 * 64];    // 8 KB
    __shared__ int   toks[128];
    __shared__ float gts[128];

    const int tid = threadIdx.x;
    if (tid < 128) {
        toks[tid] = perm[tile * 128 + tid];
        gts[tid]  = pgate[tile * 128 + tid];
    }
    __syncthreads();

    const int l = tid & 63;
    const int w = tid >> 6;
    const int lrow = l >> 3;                   // 0..7 within 8-row stripe
    const int schk = (l & 7) ^ lrow;           // swizzled source 16B chunk

    // per-lane global sources (swizzle folded in); wave-uniform LDS bases
    const unsigned short* asrc[4];
    unsigned short* aldsb[4];
#pragma unroll
    for (int i = 0; i < 4; ++i) {
        const int row = i * 32 + w * 8 + lrow;
        asrc[i]  = Xb + (size_t)toks[row] * DIN + schk * 8;
        aldsb[i] = &As[(i * 32 + w * 8) * 64];
    }
    const unsigned short* bsrc[2];
    unsigned short* bldsb[2];
#pragma unroll
    for (int j = 0; j < 2; ++j) {
        const int row = j * 32 + w * 8 + lrow;
        bsrc[j]  = WT + ((size_t)e * DOUT + n0 + row) * DIN + schk * 8;
        bldsb[j] = &Bs[(j * 32 + w * 8) * 64];
    }

    f32x4 acc[4][2];
#pragma unroll
    for (int a = 0; a < 4; ++a)
#pragma unroll
        for (int b = 0; b < 2; ++b) acc[a][b] = (f32x4){0.f, 0.f, 0.f, 0.f};

    const int wm = w >> 1, wn = w & 1;         // 2x2 waves: 64 rows x 32 cols
    const int fr = l & 15;
    const int fh = l >> 4;                     // k chunk within 32-elem half

    for (int k0 = 0; k0 < DIN; k0 += 64) {
        __syncthreads();                       // prev compute done reading LDS
#pragma unroll
        for (int i = 0; i < 4; ++i) glds16(asrc[i] + k0, aldsb[i]);
#pragma unroll
        for (int j = 0; j < 2; ++j) glds16(bsrc[j] + k0, bldsb[j]);
        __syncthreads();                       // drains vmcnt(0): data visible
#pragma unroll
        for (int ks = 0; ks < 2; ++ks) {
            bhalf8 af[4], bff[2];
#pragma unroll
            for (int fm = 0; fm < 4; ++fm)
                af[fm] = *reinterpret_cast<const bhalf8*>(
                    &As[swz(wm * 64 + fm * 16 + fr, ks * 4 + fh)]);
#pragma unroll
            for (int fn = 0; fn < 2; ++fn)
                bff[fn] = *reinterpret_cast<const bhalf8*>(
                    &Bs[swz(wn * 32 + fn * 16 + fr, ks * 4 + fh)]);
#pragma unroll
            for (int fm = 0; fm < 4; ++fm)
#pragma unroll
                for (int fn = 0; fn < 2; ++fn)
                    acc[fm][fn] = __builtin_amdgcn_mfma_f32_16x16x32_bf16(
                        af[fm], bff[fn], acc[fm][fn], 0, 0, 0);
        }
    }

    // ---- epilogue: atomic accumulate g*(acc+bias) into split output chunks
    size_t base; int width, cstart;
    if (n0 < 512)       { base = 0;                 width = 512; cstart = n0; }
    else if (n0 < 1024) { base = (size_t)NT * 512;  width = 512; cstart = n0 - 512; }
    else                { base = (size_t)NT * 1024; width = 256; cstart = n0 - 1024; }
    const int lc = l & 15, lr = l >> 4;
    const int coloff = cstart + wn * 32 + lc;
    float bval[2];
#pragma unroll
    for (int fn = 0; fn < 2; ++fn)
        bval[fn] = bexp[(size_t)e * DOUT + n0 + wn * 32 + fn * 16 + lc];
#pragma unroll
    for (int fm = 0; fm < 4; ++fm) {
#pragma unroll
        for (int j = 0; j < 4; ++j) {
            const int row = wm * 64 + fm * 16 + lr * 4 + j;
            const float gg = gts[row];
            if (gg != 0.f) {                   // dummy rows have gate 0
                float* op = out + base + (size_t)toks[row] * width + coloff;
#pragma unroll
                for (int fn = 0; fn < 2; ++fn)
                    gatomic_fadd(op + fn * 16, gg * (acc[fm][fn][j] + bval[fn]));
            }
        }
    }
}

// ---------------------------------------------------------------------------
// host launcher
// ---------------------------------------------------------------------------
extern "C" void kernel_launch(void* const* d_in, const int* in_sizes, int n_in,
                              void* d_out, int out_size, void* d_ws, size_t ws_size,
                              hipStream_t stream) {
    const float* x     = (const float*)d_in[0];
    const float* temb  = (const float*)d_in[1];
    const int*   atype = (const int*)d_in[2];
    const float* Wg    = (const float*)d_in[3];
    const float* Wexp  = (const float*)d_in[4];
    const float* bexp  = (const float*)d_in[5];
    float* out = (float*)d_out;
    char*  ws  = (char*)d_ws;

    unsigned short* xb = (unsigned short*)(ws);                        // 4 MB
    unsigned short* wt = (unsigned short*)(ws + (size_t)4194304);      // 10.5 MB
    char* meta = ws + (size_t)14680064;
    int*   e0a = (int*)(meta);
    int*   e1a = (int*)(meta + 16384);
    float* g0a = (float*)(meta + 32768);
    float* g1a = (float*)(meta + 49152);
    int*   perm        = (int*)(meta + 65536);    // 40960 B
    float* pgate       = (float*)(meta + 106496); // 40960 B
    int*   tile_expert = (int*)(meta + 147456);   // 320 B
    int*   ntiles      = (int*)(meta + 147968);   // 4 B

    hipMemsetAsync(out, 0, (size_t)out_size * sizeof(float), stream);
    gate_kernel<<<dim3(NT / 4), dim3(256), 0, stream>>>(
        x, temb, atype, Wg, xb, e0a, e1a, g0a, g1a);
    convw_kernel<<<dim3(DOUT / 64, DIN / 32, NE), dim3(64), 0, stream>>>(Wexp, wt);
    sort_kernel<<<dim3(1), dim3(SORT_T), 0, stream>>>(
        e0a, e1a, g0a, g1a, perm, pgate, tile_expert, ntiles);
    gemm_kernel<<<dim3(MAXTILES * NB), dim3(256), 0, stream>>>(
        xb, wt, bexp, perm, pgate, tile_expert, ntiles, out);
}